// Round 15
// baseline (267.918 us; speedup 1.0000x reference)
//
#include <hip/hip_runtime.h>
#include <hip/hip_fp16.h>

// ---------------------------------------------------------------------------
// GCN 3-layer forward on MI355X.  (r15: barrier-free self-paced gemm1)
// init+splitW -> deg -> scan1(+dinv) -> scan23 -> fill -> per layer:
//   L1: k_gemm_bf16 1-WAVE blocks (64 thr), wave tile 64x32, grid 782x4=3128
//       waves (~3/SIMD, independent, NO s_barrier). Per-iter VMEM queue:
//       [B(t):4][S(t+1) DMA:8] asm vmcnt(12) -> drains only S(t); compiler's
//       B(t) wait drains only B(t). Pipeline never empties (r13 failed
//       because compiler's B-wait after stage issues drained the prefetch).
//   L2: k_gemm2 (A=y1 fp16 EXACT, W fp16-split, 2 MFMA prods) -> k_agg64y
//   L3: k_gemm3 -> k_agg64out (f32 d_out)
// ---------------------------------------------------------------------------

typedef __attribute__((ext_vector_type(8))) short bf16x8;
typedef __attribute__((ext_vector_type(8))) _Float16 f16x8;
typedef __attribute__((ext_vector_type(4))) float f32x4;
typedef unsigned short u16;
typedef unsigned int u32;

static inline size_t alignup(size_t v, size_t a) { return (v + a - 1) & ~(a - 1); }

__device__ __forceinline__ u32 pack_hi16(u32 b0, u32 b1) {
    return __builtin_amdgcn_perm(b1, b0, 0x07060302u);   // top16(b0)|top16(b1)
}

// --- W1 split: fragment-ordered bf16 hi/lo -----------------------------------
__device__ __forceinline__ void splitW_bf16(const float* __restrict__ W,
                                            u16* __restrict__ Wh,
                                            u16* __restrict__ Wl, int s, int F) {
    int c = s % F;
    int kb = (s / F) * 8;
    union { u32 u[4]; bf16x8 v; } hi, lo;
#pragma unroll
    for (int p = 0; p < 4; p++) {
        float x0 = W[(size_t)(kb + 2 * p) * F + c];
        float x1 = W[(size_t)(kb + 2 * p + 1) * F + c];
        u32 b0 = __float_as_uint(x0), b1 = __float_as_uint(x1);
        float l0 = x0 - __uint_as_float(b0 & 0xFFFF0000u);
        float l1 = x1 - __uint_as_float(b1 & 0xFFFF0000u);
        hi.u[p] = pack_hi16(b0, b1);
        lo.u[p] = pack_hi16(__float_as_uint(l0), __float_as_uint(l1));
    }
    *(bf16x8*)(Wh + (size_t)s * 8) = hi.v;
    *(bf16x8*)(Wl + (size_t)s * 8) = lo.v;
}

// --- W2/W3 split: fragment-ordered fp16 hi/lo (22-bit effective) -------------
__device__ __forceinline__ void splitW_f16(const float* __restrict__ W,
                                           u16* __restrict__ Wh,
                                           u16* __restrict__ Wl, int s, int F) {
    int c = s % F;
    int kb = (s / F) * 8;
    union { u16 u[8]; bf16x8 v; } hi, lo;
#pragma unroll
    for (int p = 0; p < 8; p++) {
        float xv = W[(size_t)(kb + p) * F + c];
        __half h = __float2half(xv);
        __half l = __float2half(xv - __half2float(h));
        hi.u[p] = __half_as_ushort(h);
        lo.u[p] = __half_as_ushort(l);
    }
    *(bf16x8*)(Wh + (size_t)s * 8) = hi.v;
    *(bf16x8*)(Wl + (size_t)s * 8) = lo.v;
}

// --- init (zero deg + detect layout) fused with W splits ---------------------
__global__ void k_init_split(const int* __restrict__ ei, int* __restrict__ flag,
                             int* __restrict__ deg, int N, int nb,
                             const float* __restrict__ W1, u16* w1h, u16* w1l,
                             const float* __restrict__ W2, u16* w2h, u16* w2l,
                             const float* __restrict__ W3, u16* w3h, u16* w3l) {
    int b = blockIdx.x;
    if (b < nb) {
        int i = b * 256 + threadIdx.x;
        if (i < N) deg[i] = 0;
        if (b == 0 && threadIdx.x < 64) {
            int v = ei[2 * threadIdx.x + 1];          // high word if int64
            unsigned long long m = __ballot(v != 0);
            if (threadIdx.x == 0) *flag = (m == 0ull) ? 1 : 0;
        }
        return;
    }
    int s = (b - nb) * 256 + threadIdx.x;
    if (s < 8192) splitW_bf16(W1, w1h, w1l, s, 128);              // 512x128/8
    else if (s < 9216) splitW_f16(W2, w2h, w2l, s - 8192, 64);    // 128x64/8
    else if (s < 9728) splitW_f16(W3, w3h, w3l, s - 9216, 64);    // 64x64/8
}

__global__ void k_deg(const int* __restrict__ ei, int E,
                      const int* __restrict__ flag, int* __restrict__ deg) {
    int i = blockIdx.x * blockDim.x + threadIdx.x;
    if (i >= E) return;
    int is64 = *flag;
    int d = is64 ? ei[2 * (E + i)] : ei[E + i];
    atomicAdd(&deg[d], 1);
}

__global__ void k_scan1(const int* __restrict__ deg, int* __restrict__ offs,
                        int* __restrict__ bsums, float* __restrict__ dinv, int N) {
    __shared__ int s[256];
    int i = blockIdx.x * 256 + threadIdx.x;
    int v = (i < N) ? deg[i] : 0;
    if (i < N) dinv[i] = rsqrtf((float)v + 1.0f);
    s[threadIdx.x] = v;
    __syncthreads();
    for (int off = 1; off < 256; off <<= 1) {
        int t = (threadIdx.x >= off) ? s[threadIdx.x - off] : 0;
        __syncthreads();
        s[threadIdx.x] += t;
        __syncthreads();
    }
    if (i < N) offs[i] = s[threadIdx.x] - v;   // exclusive
    if (threadIdx.x == 255) bsums[blockIdx.x] = s[255];
}

__global__ void k_scan23(int* __restrict__ offs, const int* __restrict__ bsums,
                         int nb, int N, int E) {
    __shared__ int s[256];
    int tid = threadIdx.x;
    s[tid] = (tid < nb) ? bsums[tid] : 0;
    __syncthreads();
    for (int off = 1; off < 256; off <<= 1) {
        int t = (tid >= off) ? s[tid - off] : 0;
        __syncthreads();
        s[tid] += t;                 // inclusive scan
        __syncthreads();
    }
    int boff = (blockIdx.x > 0) ? s[blockIdx.x - 1] : 0;
    int i = blockIdx.x * 256 + tid;
    if (i < N) offs[i] += boff;
    if (i == 0) offs[N] = E;
}

__global__ void k_fill(const int* __restrict__ ei, int E,
                       const int* __restrict__ flag,
                       const int* __restrict__ offs, int* __restrict__ deg,
                       int* __restrict__ csr) {
    int i = blockIdx.x * blockDim.x + threadIdx.x;
    if (i >= E) return;
    int is64 = *flag;
    int s = is64 ? ei[2 * i] : ei[i];
    int d = is64 ? ei[2 * (E + i)] : ei[E + i];
    int slot = offs[d] + atomicSub(&deg[d], 1) - 1;
    csr[slot] = s;
}

// --- L1 GEMM: H'[N,128] = dinv * (X[N,512] @ W1), bf16x3, fp16 out -----------
// 1-wave blocks (64 thr). Wave tile 64 rows x 32 cols (MF=4, NF=2).
// Grid = rowtiles*4 col-quarters. A K-tile [64][32] f32 double-buffered in
// LDS via global_load_lds (self-paced counted vmcnt; NO barriers).
__global__ __launch_bounds__(64, 4) void k_gemm_bf16(
        const float* __restrict__ X,
        const u16* __restrict__ Wh, const u16* __restrict__ Wl,
        const float* __restrict__ dinv, __half* __restrict__ Hh, int N) {
    constexpr int K = 512, F = 128, MF = 4, NF = 2, NT = K / 32;
    __shared__ float4 smemA[2][512];   // 2 x 8 KB

    const int lane = threadIdx.x;      // 1 wave
    const int colbase = (blockIdx.x & 3) * 32;
    const int row0 = (blockIdx.x >> 2) * 64;
    const int lg = lane >> 4, li = lane & 15;

    // stage K-tile t: lds chunk c_lin=(j*64+lane) holds
    // X[row0 + c_lin>>3][t*32 + ((c_lin&7)^(row&7))*4 ..+3]   (8 DMA / lane)
    auto stage = [&](int b, int t) {
#pragma unroll
        for (int j = 0; j < 8; j++) {
            int c_lin = j * 64 + lane;
            int row = c_lin >> 3, c = c_lin & 7;
            int rg = row0 + row;
            if (rg >= N) rg = N - 1;
            int cs = c ^ (row & 7);
            const float* g = X + (size_t)rg * K + t * 32 + cs * 4;
            char* l = (char*)&smemA[b][0] + j * 1024;   // + lane*16 by HW
            __builtin_amdgcn_global_load_lds(
                (const __attribute__((address_space(1))) void*)g,
                (__attribute__((address_space(3))) void*)l, 16, 0, 0);
        }
    };

    f32x4 acc[MF][NF];
#pragma unroll
    for (int m = 0; m < MF; m++)
#pragma unroll
        for (int n = 0; n < NF; n++) acc[m][n] = (f32x4){0.f, 0.f, 0.f, 0.f};

    stage(0, 0);                        // 8 outstanding; NOT drained here

    for (int t = 0; t < NT; t++) {
        const int b = t & 1;
        // B(t) register loads FIRST (older than S(t+1) in the vmcnt queue,
        // so the compiler's wait for them never drains the stage prefetch)
        bf16x8 bh[NF], bl[NF];
        size_t slot0 = (size_t)(t * 4 + lg) * F + colbase + li;
#pragma unroll
        for (int n = 0; n < NF; n++) {
            bh[n] = *(const bf16x8*)(Wh + (slot0 + n * 16) * 8);
            bl[n] = *(const bf16x8*)(Wl + (slot0 + n * 16) * 8);
        }
        __builtin_amdgcn_sched_barrier(0);
        if (t + 1 < NT) {
            stage(b ^ 1, t + 1);        // async DMA, stays in flight
            __builtin_amdgcn_sched_barrier(0);
            // queue: [S(t):8, B(t):4, S(t+1):8] -> drain exactly S(t)
            asm volatile("s_waitcnt vmcnt(12)" ::: "memory");
        } else {
            // queue: [S(t):8, B(t):4] -> drain exactly S(t)
            asm volatile("s_waitcnt vmcnt(4)" ::: "memory");
        }
        __builtin_amdgcn_sched_barrier(0);
        // A(t) from LDS (swizzled b128 reads) -> bf16 hi/lo split
        const float4* lt = &smemA[b][0];
        bf16x8 ah[MF], al[MF];
#pragma unroll
        for (int m = 0; m < MF; m++) {
            int row = m * 16 + li;
            int base = row * 8, sw = row & 7;
            float4 c0 = lt[base + ((2 * lg) ^ sw)];
            float4 c1 = lt[base + ((2 * lg + 1) ^ sw)];
            float xv[8] = {c0.x, c0.y, c0.z, c0.w, c1.x, c1.y, c1.z, c1.w};
            union { u32 u[4]; bf16x8 v; } hi, lo;
#pragma unroll
            for (int q = 0; q < 4; q++) {
                u32 b0 = __float_as_uint(xv[2 * q]);
                u32 b1 = __float_as_uint(xv[2 * q + 1]);
                float l0 = xv[2 * q]     - __uint_as_float(b0 & 0xFFFF0000u);
                float l1 = xv[2 * q + 1] - __uint_as_float(b1 & 0xFFFF0000u);
                hi.u[q] = pack_hi16(b0, b1);
                lo.u[q] = pack_hi16(__float_as_uint(l0), __float_as_uint(l1));
            }
            ah[m] = hi.v;
            al[m] = lo.v;
        }
        // 3-product accumulation (compiler inserts wait for B(t) only here)
#pragma unroll
        for (int m = 0; m < MF; m++)
#pragma unroll
            for (int n = 0; n < NF; n++) {
                acc[m][n] = __builtin_amdgcn_mfma_f32_16x16x32_bf16(ah[m], bh[n], acc[m][n], 0, 0, 0);
                acc[m][n] = __builtin_amdgcn_mfma_f32_16x16x32_bf16(ah[m], bl[n], acc[m][n], 0, 0, 0);
                acc[m][n] = __builtin_amdgcn_mfma_f32_16x16x32_bf16(al[m], bh[n], acc[m][n], 0, 0, 0);
            }
    }

    // C/D layout: col = lane&15, row = (lane>>4)*4 + reg (m89-verified)
#pragma unroll
    for (int m = 0; m < MF; m++) {
        int rb = row0 + m * 16 + lg * 4;
#pragma unroll
        for (int r = 0; r < 4; r++) {
            int gr = rb + r;
            if (gr >= N) continue;
            float di = dinv[gr];
#pragma unroll
            for (int n = 0; n < NF; n++) {
                int col = colbase + n * 16 + li;
                Hh[(size_t)gr * F + col] = __float2half(acc[m][n][r] * di);
            }
        }
    }
}

// --- L2/L3 GEMM body: H'[N,64] = dinv * (Y[N,K] @ W), Y fp16 EXACT -----------
// 128 thr = 2 waves (col halves), wave tile 64x32 (MF=4, NF=2), 2 MFMA prods.
template <int K>
__device__ __forceinline__ void gemm_f16_body(
        const __half* __restrict__ Y,
        const u16* __restrict__ Wh, const u16* __restrict__ Wl,
        const float* __restrict__ dinv, __half* __restrict__ Hh, int N) {
    constexpr int F = 64, MF = 4, NF = 2, NT = K / 32;
    __shared__ float4 smemA[2][256];   // 2 x 4 KB

    const int tid = threadIdx.x;
    const int lane = tid & 63;
    const int w = tid >> 6;
    const int colbase = w * (NF * 16);
    const int lg = lane >> 4, li = lane & 15;
    const int row0 = blockIdx.x * 64;

    auto stage = [&](int b, int t) {
#pragma unroll
        for (int j = 0; j < 2; j++) {
            int c_lin = j * 128 + tid;          // 0..255
            int row = c_lin >> 2, c = c_lin & 3;
            int rg = row0 + row;
            if (rg >= N) rg = N - 1;
            int cs = c ^ (row & 3);
            const __half* g = Y + (size_t)rg * K + t * 32 + cs * 8;  // 16 B
            char* l = (char*)&smemA[b][0] + j * 2048 + w * 1024;
            __builtin_amdgcn_global_load_lds(
                (const __attribute__((address_space(1))) void*)g,
                (__attribute__((address_space(3))) void*)l, 16, 0, 0);
        }
    };

    f32x4 acc[MF][NF];
#pragma unroll
    for (int m = 0; m < MF; m++)
#pragma unroll
        for (int n = 0; n < NF; n++) acc[m][n] = (f32x4){0.f, 0.f, 0.f, 0.f};

    stage(0, 0);
    __syncthreads();

    for (int t = 0; t < NT; t++) {
        const int b = t & 1;
        f16x8 bh[NF], bl[NF];
        size_t slot0 = (size_t)(t * 4 + lg) * F + colbase + li;
#pragma unroll
        for (int n = 0; n < NF; n++) {
            bh[n] = *(const f16x8*)(Wh + (slot0 + n * 16) * 8);
            bl[n] = *(const f16x8*)(Wl + (slot0 + n * 16) * 8);
        }
        __builtin_amdgcn_sched_barrier(0);
        if (t + 1 < NT) stage(b ^ 1, t + 1);
        const float4* lt = &smemA[b][0];
        f16x8 a[MF];
#pragma unroll
        for (int m = 0; m < MF; m++) {
            int row = m * 16 + li;
            union { float4 f; f16x8 h; } u;
            u.f = lt[row * 4 + (lg ^ (row & 3))];
            a[m] = u.h;
        }
#pragma unroll
        for (int m = 0; m < MF; m++)
#pragma unroll
            for (int n = 0; n < NF; n++) {
                acc[m][n] = __builtin_amdgcn_mfma_f32_16x16x32_f16(a[m], bh[n], acc[m][n], 0, 0, 0);
                acc[m][n] = __builtin_amdgcn_mfma_f32_16x16x32_f16(a[m], bl[n], acc[m][n], 0, 0, 0);
            }
        __syncthreads();
    }

#pragma unroll
    for (int m = 0; m < MF; m++) {
        int rb = row0 + m * 16 + lg * 4;
#pragma unroll
        for (int r = 0; r < 4; r++) {
            int gr = rb + r;
            if (gr >= N) continue;
            float di = dinv[gr];
#pragma unroll
            for (int n = 0; n < NF; n++) {
                int col = colbase + n * 16 + li;
                Hh[(size_t)gr * F + col] = __float2half(acc[m][n][r] * di);
            }
        }
    }
}

__global__ __launch_bounds__(128) void k_gemm2(
        const __half* __restrict__ Y, const u16* __restrict__ Wh,
        const u16* __restrict__ Wl, const float* __restrict__ dinv,
        __half* __restrict__ Hh, int N) {
    gemm_f16_body<128>(Y, Wh, Wl, dinv, Hh, N);
}
__global__ __launch_bounds__(128) void k_gemm3(
        const __half* __restrict__ Y, const u16* __restrict__ Wh,
        const u16* __restrict__ Wl, const float* __restrict__ dinv,
        __half* __restrict__ Hh, int N) {
    gemm_f16_body<64>(Y, Wh, Wl, dinv, Hh, N);
}

// --- agg, F=128, fp16 H' in, fp16 y out (leaky-relu) --------------------------
__global__ __launch_bounds__(256) void k_agg128(const __half* __restrict__ Hh,
                                                const int* __restrict__ offs,
                                                const int* __restrict__ csr,
                                                const float* __restrict__ dinv,
                                                const float* __restrict__ bias,
                                                __half* __restrict__ Y, int N) {
    int node = blockIdx.x * 4 + (threadIdx.x >> 6);
    int lane = threadIdx.x & 63;
    if (node >= N) return;
    const __half2* H2 = (const __half2*)Hh;   // row = 64 half2
    float ax = 0.f, ay = 0.f;
    int o0 = offs[node], o1 = offs[node + 1];
    int e = o0;
    for (; e + 4 <= o1; e += 4) {
        int s0 = csr[e], s1 = csr[e + 1], s2 = csr[e + 2], s3 = csr[e + 3];
        float2 f0 = __half22float2(H2[(size_t)s0 * 64 + lane]);
        float2 f1 = __half22float2(H2[(size_t)s1 * 64 + lane]);
        float2 f2 = __half22float2(H2[(size_t)s2 * 64 + lane]);
        float2 f3 = __half22float2(H2[(size_t)s3 * 64 + lane]);
        ax += (f0.x + f1.x) + (f2.x + f3.x);
        ay += (f0.y + f1.y) + (f2.y + f3.y);
    }
    for (; e < o1; ++e) {
        float2 f0 = __half22float2(H2[(size_t)csr[e] * 64 + lane]);
        ax += f0.x; ay += f0.y;
    }
    float2 fs = __half22float2(H2[(size_t)node * 64 + lane]);
    float di = dinv[node];
    float2 bv = ((const float2*)bias)[lane];
    float vx = di * (ax + fs.x) + bv.x;
    float vy = di * (ay + fs.y) + bv.y;
    vx = vx > 0.f ? vx : 0.2f * vx;
    vy = vy > 0.f ? vy : 0.2f * vy;
    ((__half2*)Y)[(size_t)node * 64 + lane] = __floats2half2_rn(vx, vy);
}

// --- agg, F=64, fp16 H' in — shared body, fp16-y or f32-out variants ---------
template <bool RELU, bool OUT16>
__device__ __forceinline__ void agg64_body(const __half* __restrict__ Hh,
                                           const int* __restrict__ offs,
                                           const int* __restrict__ csr,
                                           const float* __restrict__ dinv,
                                           const float* __restrict__ bias,
                                           void* __restrict__ Y, int N) {
    int node = blockIdx.x * 8 + (threadIdx.x >> 5);
    int lane = threadIdx.x & 31;
    if (node >= N) return;
    const __half2* H2 = (const __half2*)Hh;   // row = 32 half2
    float ax = 0.f, ay = 0.f;
    int o0 = offs[node], o1 = offs[node + 1];
    int e = o0;
    for (; e + 4 <= o1; e += 4) {
        int s0 = csr[e], s1 = csr[e + 1], s2 = csr[e + 2], s3 = csr[e + 3];
        float2 f0 = __half22float2(H2[(size_t)s0 * 32 + lane]);
        float2 f1 = __half22float2(H2[(size_t)s1 * 32 + lane]);
        float2 f2 = __half22float2(H2[(size_t)s2 * 32 + lane]);
        float2 f3 = __half22float2(H2[(size_t)s3 * 32 + lane]);
        ax += (f0.x + f1.x) + (f2.x + f3.x);
        ay += (f0.y + f1.y) + (f2.y + f3.y);
    }
    for (; e < o1; ++e) {
        float2 f0 = __half22float2(H2[(size_t)csr[e] * 32 + lane]);
        ax += f0.x; ay += f0.y;
    }
    float2 fs = __half22float2(H2[(size_t)node * 32 + lane]);
    float di = dinv[node];
    float2 bv = ((const float2*)bias)[lane];
    float vx = di * (ax + fs.x) + bv.x;
    float vy = di * (ay + fs.y) + bv.y;
    if (RELU) { vx = vx > 0.f ? vx : 0.2f * vx; vy = vy > 0.f ? vy : 0.2f * vy; }
    if (OUT16)
        ((__half2*)Y)[(size_t)node * 32 + lane] = __floats2half2_rn(vx, vy);
    else
        ((float2*)Y)[(size_t)node * 32 + lane] = make_float2(vx, vy);
}

__global__ __launch_bounds__(256) void k_agg64y(const __half* Hh, const int* offs,
                                                const int* csr, const float* dinv,
                                                const float* bias, __half* Y, int N) {
    agg64_body<true, true>(Hh, offs, csr, dinv, bias, Y, N);
}
__global__ __launch_bounds__(256) void k_agg64out(const __half* Hh, const int* offs,
                                                  const int* csr, const float* dinv,
                                                  const float* bias, float* Y, int N) {
    agg64_body<false, false>(Hh, offs, csr, dinv, bias, Y, N);
}

extern "C" void kernel_launch(void* const* d_in, const int* in_sizes, int n_in,
                              void* d_out, int out_size, void* d_ws, size_t ws_size,
                              hipStream_t stream) {
    const float* x  = (const float*)d_in[0];
    const int*   ei = (const int*)d_in[1];
    const float* W1 = (const float*)d_in[2];
    const float* b1 = (const float*)d_in[3];
    const float* W2 = (const float*)d_in[4];
    const float* b2 = (const float*)d_in[5];
    const float* W3 = (const float*)d_in[6];
    const float* b3 = (const float*)d_in[7];

    const int N = in_sizes[0] / 512;
    const int E = in_sizes[1] / 2;
    const int nb = (N + 255) / 256;

    char* w = (char*)d_ws;
    auto take = [&](size_t bytes) -> char* {
        char* p = w;
        w += alignup(bytes, 256);
        return p;
    };
    int*    flag  = (int*)take(256);
    int*    deg   = (int*)take((size_t)N * 4);
    int*    offs  = (int*)take((size_t)(N + 1) * 4);
    int*    bsums = (int*)take((size_t)nb * 4);
    int*    csr   = (int*)take((size_t)E * 4);
    float*  dinv  = (float*)take((size_t)N * 4);
    __half* bufA  = (__half*)take((size_t)N * 128 * 2);   // H' fp16
    __half* bufY  = (__half*)take((size_t)N * 128 * 2);   // y fp16
    u16*    w1h   = (u16*)take((size_t)512 * 128 * 2);
    u16*    w1l   = (u16*)take((size_t)512 * 128 * 2);
    u16*    w2h   = (u16*)take((size_t)128 * 64 * 2);
    u16*    w2l   = (u16*)take((size_t)128 * 64 * 2);
    u16*    w3h   = (u16*)take((size_t)64 * 64 * 2);
    u16*    w3l   = (u16*)take((size_t)64 * 64 * 2);

    const int TB = 256;
    // preprocessing (5 launches)
    k_init_split<<<nb + 38, TB, 0, stream>>>(ei, flag, deg, N, nb,
                                             W1, w1h, w1l, W2, w2h, w2l,
                                             W3, w3h, w3l);
    k_deg<<<(E + TB - 1) / TB, TB, 0, stream>>>(ei, E, flag, deg);
    k_scan1<<<nb, 256, 0, stream>>>(deg, offs, bsums, dinv, N);
    k_scan23<<<nb, 256, 0, stream>>>(offs, bsums, nb, N, E);
    k_fill<<<(E + TB - 1) / TB, TB, 0, stream>>>(ei, E, flag, offs, deg, csr);

    const int rowtiles = (N + 63) / 64;
    // layer 1: 1-wave blocks, 4 col-quarters per row tile
    k_gemm_bf16<<<rowtiles * 4, 64, 0, stream>>>(x, w1h, w1l, dinv, bufA, N);
    k_agg128<<<(N + 3) / 4, 256, 0, stream>>>(bufA, offs, csr, dinv, b1, bufY, N);
    // layer 2
    k_gemm2<<<rowtiles, 128, 0, stream>>>(bufY, w2h, w2l, dinv, bufA, N);
    k_agg64y<<<(N + 7) / 8, 256, 0, stream>>>(bufA, offs, csr, dinv, b2, bufY, N);
    // layer 3
    k_gemm3<<<rowtiles, 128, 0, stream>>>(bufY, w3h, w3l, dinv, bufA, N);
    k_agg64out<<<(N + 7) / 8, 256, 0, stream>>>(bufA, offs, csr, dinv, b3,
                                                (float*)d_out, N);
}

// Round 16
// 248.907 us; speedup vs baseline: 1.0764x; 1.0764x over previous
//
#include <hip/hip_runtime.h>
#include <hip/hip_fp16.h>

// ---------------------------------------------------------------------------
// GCN 3-layer forward on MI355X.  (r16: 4-wave shared-stage gemm1)
// init+splitW -> deg -> scan1(+dinv) -> scan23 -> fill -> per layer:
//   L1: k_gemm_bf16 256-thr blocks = 4 waves as 4 COL-QUARTERS sharing ONE
//       staged A tile (64 rows x 32 k, dbuf LDS via global_load_lds).
//       r15 post-mortem: 1-wave col-quarter blocks re-fetched X 4x (FETCH
//       51->201 MB) but proved HBM delivers 2.9 TB/s at 3 waves/SIMD.
//       This keeps r15's occupancy (782 blocks x 4 waves = 3/SIMD) with
//       r11's single-fetch traffic. Wave tile 64x32 (MF=4, NF=2).
//   L2: k_gemm2 (A=y1 fp16 EXACT, W fp16-split, 2 MFMA prods) -> k_agg64y
//   L3: k_gemm3 -> k_agg64out (f32 d_out)
// ---------------------------------------------------------------------------

typedef __attribute__((ext_vector_type(8))) short bf16x8;
typedef __attribute__((ext_vector_type(8))) _Float16 f16x8;
typedef __attribute__((ext_vector_type(4))) float f32x4;
typedef unsigned short u16;
typedef unsigned int u32;

static inline size_t alignup(size_t v, size_t a) { return (v + a - 1) & ~(a - 1); }

__device__ __forceinline__ u32 pack_hi16(u32 b0, u32 b1) {
    return __builtin_amdgcn_perm(b1, b0, 0x07060302u);   // top16(b0)|top16(b1)
}

// --- W1 split: fragment-ordered bf16 hi/lo -----------------------------------
__device__ __forceinline__ void splitW_bf16(const float* __restrict__ W,
                                            u16* __restrict__ Wh,
                                            u16* __restrict__ Wl, int s, int F) {
    int c = s % F;
    int kb = (s / F) * 8;
    union { u32 u[4]; bf16x8 v; } hi, lo;
#pragma unroll
    for (int p = 0; p < 4; p++) {
        float x0 = W[(size_t)(kb + 2 * p) * F + c];
        float x1 = W[(size_t)(kb + 2 * p + 1) * F + c];
        u32 b0 = __float_as_uint(x0), b1 = __float_as_uint(x1);
        float l0 = x0 - __uint_as_float(b0 & 0xFFFF0000u);
        float l1 = x1 - __uint_as_float(b1 & 0xFFFF0000u);
        hi.u[p] = pack_hi16(b0, b1);
        lo.u[p] = pack_hi16(__float_as_uint(l0), __float_as_uint(l1));
    }
    *(bf16x8*)(Wh + (size_t)s * 8) = hi.v;
    *(bf16x8*)(Wl + (size_t)s * 8) = lo.v;
}

// --- W2/W3 split: fragment-ordered fp16 hi/lo (22-bit effective) -------------
__device__ __forceinline__ void splitW_f16(const float* __restrict__ W,
                                           u16* __restrict__ Wh,
                                           u16* __restrict__ Wl, int s, int F) {
    int c = s % F;
    int kb = (s / F) * 8;
    union { u16 u[8]; bf16x8 v; } hi, lo;
#pragma unroll
    for (int p = 0; p < 8; p++) {
        float xv = W[(size_t)(kb + p) * F + c];
        __half h = __float2half(xv);
        __half l = __float2half(xv - __half2float(h));
        hi.u[p] = __half_as_ushort(h);
        lo.u[p] = __half_as_ushort(l);
    }
    *(bf16x8*)(Wh + (size_t)s * 8) = hi.v;
    *(bf16x8*)(Wl + (size_t)s * 8) = lo.v;
}

// --- init (zero deg + detect layout) fused with W splits ---------------------
__global__ void k_init_split(const int* __restrict__ ei, int* __restrict__ flag,
                             int* __restrict__ deg, int N, int nb,
                             const float* __restrict__ W1, u16* w1h, u16* w1l,
                             const float* __restrict__ W2, u16* w2h, u16* w2l,
                             const float* __restrict__ W3, u16* w3h, u16* w3l) {
    int b = blockIdx.x;
    if (b < nb) {
        int i = b * 256 + threadIdx.x;
        if (i < N) deg[i] = 0;
        if (b == 0 && threadIdx.x < 64) {
            int v = ei[2 * threadIdx.x + 1];          // high word if int64
            unsigned long long m = __ballot(v != 0);
            if (threadIdx.x == 0) *flag = (m == 0ull) ? 1 : 0;
        }
        return;
    }
    int s = (b - nb) * 256 + threadIdx.x;
    if (s < 8192) splitW_bf16(W1, w1h, w1l, s, 128);              // 512x128/8
    else if (s < 9216) splitW_f16(W2, w2h, w2l, s - 8192, 64);    // 128x64/8
    else if (s < 9728) splitW_f16(W3, w3h, w3l, s - 9216, 64);    // 64x64/8
}

__global__ void k_deg(const int* __restrict__ ei, int E,
                      const int* __restrict__ flag, int* __restrict__ deg) {
    int i = blockIdx.x * blockDim.x + threadIdx.x;
    if (i >= E) return;
    int is64 = *flag;
    int d = is64 ? ei[2 * (E + i)] : ei[E + i];
    atomicAdd(&deg[d], 1);
}

__global__ void k_scan1(const int* __restrict__ deg, int* __restrict__ offs,
                        int* __restrict__ bsums, float* __restrict__ dinv, int N) {
    __shared__ int s[256];
    int i = blockIdx.x * 256 + threadIdx.x;
    int v = (i < N) ? deg[i] : 0;
    if (i < N) dinv[i] = rsqrtf((float)v + 1.0f);
    s[threadIdx.x] = v;
    __syncthreads();
    for (int off = 1; off < 256; off <<= 1) {
        int t = (threadIdx.x >= off) ? s[threadIdx.x - off] : 0;
        __syncthreads();
        s[threadIdx.x] += t;
        __syncthreads();
    }
    if (i < N) offs[i] = s[threadIdx.x] - v;   // exclusive
    if (threadIdx.x == 255) bsums[blockIdx.x] = s[255];
}

__global__ void k_scan23(int* __restrict__ offs, const int* __restrict__ bsums,
                         int nb, int N, int E) {
    __shared__ int s[256];
    int tid = threadIdx.x;
    s[tid] = (tid < nb) ? bsums[tid] : 0;
    __syncthreads();
    for (int off = 1; off < 256; off <<= 1) {
        int t = (tid >= off) ? s[tid - off] : 0;
        __syncthreads();
        s[tid] += t;                 // inclusive scan
        __syncthreads();
    }
    int boff = (blockIdx.x > 0) ? s[blockIdx.x - 1] : 0;
    int i = blockIdx.x * 256 + tid;
    if (i < N) offs[i] += boff;
    if (i == 0) offs[N] = E;
}

__global__ void k_fill(const int* __restrict__ ei, int E,
                       const int* __restrict__ flag,
                       const int* __restrict__ offs, int* __restrict__ deg,
                       int* __restrict__ csr) {
    int i = blockIdx.x * blockDim.x + threadIdx.x;
    if (i >= E) return;
    int is64 = *flag;
    int s = is64 ? ei[2 * i] : ei[i];
    int d = is64 ? ei[2 * (E + i)] : ei[E + i];
    int slot = offs[d] + atomicSub(&deg[d], 1) - 1;
    csr[slot] = s;
}

// --- L1 GEMM: H'[N,128] = dinv * (X[N,512] @ W1), bf16x3, fp16 out -----------
// 256 thr = 4 waves, each one COL-QUARTER (colbase = w*32) of a shared
// 64-row x 128-col block tile. Wave tile 64x32 (MF=4, NF=2). A K-tile
// [64][32] f32 staged ONCE per block (dbuf LDS, global_load_lds, src
// chunk-swizzle c^=(row&7)); grid 782 -> 12 waves/CU = 3/SIMD.
__global__ __launch_bounds__(256) void k_gemm_bf16(
        const float* __restrict__ X,
        const u16* __restrict__ Wh, const u16* __restrict__ Wl,
        const float* __restrict__ dinv, __half* __restrict__ Hh, int N) {
    constexpr int K = 512, F = 128, MF = 4, NF = 2, NT = K / 32;
    __shared__ float4 smemA[2][512];   // 2 x 8 KB

    const int tid = threadIdx.x;
    const int lane = tid & 63;
    const int w = tid >> 6;            // 0..3 column quarter
    const int colbase = w * 32;
    const int lg = lane >> 4, li = lane & 15;
    const int row0 = blockIdx.x * 64;

    // stage K-tile t: lds chunk c_lin=(j*256+tid) holds
    // X[row0 + c_lin>>3][t*32 + ((c_lin&7)^(row&7))*4 ..+3]   (2 DMA / thr)
    auto stage = [&](int b, int t) {
#pragma unroll
        for (int j = 0; j < 2; j++) {
            int c_lin = j * 256 + tid;
            int row = c_lin >> 3, c = c_lin & 7;
            int rg = row0 + row;
            if (rg >= N) rg = N - 1;
            int cs = c ^ (row & 7);
            const float* g = X + (size_t)rg * K + t * 32 + cs * 4;
            // dest: wave-uniform base + lane*16 (m104)
            char* l = (char*)&smemA[b][0] + j * 4096 + w * 1024;
            __builtin_amdgcn_global_load_lds(
                (const __attribute__((address_space(1))) void*)g,
                (__attribute__((address_space(3))) void*)l, 16, 0, 0);
        }
    };

    f32x4 acc[MF][NF];
#pragma unroll
    for (int m = 0; m < MF; m++)
#pragma unroll
        for (int n = 0; n < NF; n++) acc[m][n] = (f32x4){0.f, 0.f, 0.f, 0.f};

    stage(0, 0);
    __syncthreads();

    for (int t = 0; t < NT; t++) {
        const int b = t & 1;
        // B(t) loads FIRST (their wait must not drain the stage DMA)
        bf16x8 bh[NF], bl[NF];
        size_t slot0 = (size_t)(t * 4 + lg) * F + colbase + li;
#pragma unroll
        for (int n = 0; n < NF; n++) {
            bh[n] = *(const bf16x8*)(Wh + (slot0 + n * 16) * 8);
            bl[n] = *(const bf16x8*)(Wl + (slot0 + n * 16) * 8);
        }
        __builtin_amdgcn_sched_barrier(0);
        if (t + 1 < NT) stage(b ^ 1, t + 1); // async DMA, drained at barrier
        // A(t) from LDS (swizzled b128 reads) -> bf16 hi/lo split
        const float4* lt = &smemA[b][0];
        bf16x8 ah[MF], al[MF];
#pragma unroll
        for (int m = 0; m < MF; m++) {
            int row = m * 16 + li;
            int base = row * 8, sw = row & 7;
            float4 c0 = lt[base + ((2 * lg) ^ sw)];
            float4 c1 = lt[base + ((2 * lg + 1) ^ sw)];
            float xv[8] = {c0.x, c0.y, c0.z, c0.w, c1.x, c1.y, c1.z, c1.w};
            union { u32 u[4]; bf16x8 v; } hi, lo;
#pragma unroll
            for (int q = 0; q < 4; q++) {
                u32 b0 = __float_as_uint(xv[2 * q]);
                u32 b1 = __float_as_uint(xv[2 * q + 1]);
                float l0 = xv[2 * q]     - __uint_as_float(b0 & 0xFFFF0000u);
                float l1 = xv[2 * q + 1] - __uint_as_float(b1 & 0xFFFF0000u);
                hi.u[q] = pack_hi16(b0, b1);
                lo.u[q] = pack_hi16(__float_as_uint(l0), __float_as_uint(l1));
            }
            ah[m] = hi.v;
            al[m] = lo.v;
        }
        // 3-product accumulation: xh*wh + xh*wl + xl*wh
#pragma unroll
        for (int m = 0; m < MF; m++)
#pragma unroll
            for (int n = 0; n < NF; n++) {
                acc[m][n] = __builtin_amdgcn_mfma_f32_16x16x32_bf16(ah[m], bh[n], acc[m][n], 0, 0, 0);
                acc[m][n] = __builtin_amdgcn_mfma_f32_16x16x32_bf16(ah[m], bl[n], acc[m][n], 0, 0, 0);
                acc[m][n] = __builtin_amdgcn_mfma_f32_16x16x32_bf16(al[m], bh[n], acc[m][n], 0, 0, 0);
            }
        __syncthreads();   // drains stage(t+1) DMA + releases buf b
    }

    // C/D layout: col = lane&15, row = (lane>>4)*4 + reg (m89-verified)
#pragma unroll
    for (int m = 0; m < MF; m++) {
        int rb = row0 + m * 16 + lg * 4;
#pragma unroll
        for (int r = 0; r < 4; r++) {
            int gr = rb + r;
            if (gr >= N) continue;
            float di = dinv[gr];
#pragma unroll
            for (int n = 0; n < NF; n++) {
                int col = colbase + n * 16 + li;
                Hh[(size_t)gr * F + col] = __float2half(acc[m][n][r] * di);
            }
        }
    }
}

// --- L2/L3 GEMM body: H'[N,64] = dinv * (Y[N,K] @ W), Y fp16 EXACT -----------
// 128 thr = 2 waves (col halves), wave tile 64x32 (MF=4, NF=2), 2 MFMA prods.
template <int K>
__device__ __forceinline__ void gemm_f16_body(
        const __half* __restrict__ Y,
        const u16* __restrict__ Wh, const u16* __restrict__ Wl,
        const float* __restrict__ dinv, __half* __restrict__ Hh, int N) {
    constexpr int F = 64, MF = 4, NF = 2, NT = K / 32;
    __shared__ float4 smemA[2][256];   // 2 x 4 KB

    const int tid = threadIdx.x;
    const int lane = tid & 63;
    const int w = tid >> 6;
    const int colbase = w * (NF * 16);
    const int lg = lane >> 4, li = lane & 15;
    const int row0 = blockIdx.x * 64;

    auto stage = [&](int b, int t) {
#pragma unroll
        for (int j = 0; j < 2; j++) {
            int c_lin = j * 128 + tid;          // 0..255
            int row = c_lin >> 2, c = c_lin & 3;
            int rg = row0 + row;
            if (rg >= N) rg = N - 1;
            int cs = c ^ (row & 3);
            const __half* g = Y + (size_t)rg * K + t * 32 + cs * 8;  // 16 B
            char* l = (char*)&smemA[b][0] + j * 2048 + w * 1024;
            __builtin_amdgcn_global_load_lds(
                (const __attribute__((address_space(1))) void*)g,
                (__attribute__((address_space(3))) void*)l, 16, 0, 0);
        }
    };

    f32x4 acc[MF][NF];
#pragma unroll
    for (int m = 0; m < MF; m++)
#pragma unroll
        for (int n = 0; n < NF; n++) acc[m][n] = (f32x4){0.f, 0.f, 0.f, 0.f};

    stage(0, 0);
    __syncthreads();

    for (int t = 0; t < NT; t++) {
        const int b = t & 1;
        f16x8 bh[NF], bl[NF];
        size_t slot0 = (size_t)(t * 4 + lg) * F + colbase + li;
#pragma unroll
        for (int n = 0; n < NF; n++) {
            bh[n] = *(const f16x8*)(Wh + (slot0 + n * 16) * 8);
            bl[n] = *(const f16x8*)(Wl + (slot0 + n * 16) * 8);
        }
        __builtin_amdgcn_sched_barrier(0);
        if (t + 1 < NT) stage(b ^ 1, t + 1);
        const float4* lt = &smemA[b][0];
        f16x8 a[MF];
#pragma unroll
        for (int m = 0; m < MF; m++) {
            int row = m * 16 + li;
            union { float4 f; f16x8 h; } u;
            u.f = lt[row * 4 + (lg ^ (row & 3))];
            a[m] = u.h;
        }
#pragma unroll
        for (int m = 0; m < MF; m++)
#pragma unroll
            for (int n = 0; n < NF; n++) {
                acc[m][n] = __builtin_amdgcn_mfma_f32_16x16x32_f16(a[m], bh[n], acc[m][n], 0, 0, 0);
                acc[m][n] = __builtin_amdgcn_mfma_f32_16x16x32_f16(a[m], bl[n], acc[m][n], 0, 0, 0);
            }
        __syncthreads();
    }

#pragma unroll
    for (int m = 0; m < MF; m++) {
        int rb = row0 + m * 16 + lg * 4;
#pragma unroll
        for (int r = 0; r < 4; r++) {
            int gr = rb + r;
            if (gr >= N) continue;
            float di = dinv[gr];
#pragma unroll
            for (int n = 0; n < NF; n++) {
                int col = colbase + n * 16 + li;
                Hh[(size_t)gr * F + col] = __float2half(acc[m][n][r] * di);
            }
        }
    }
}

__global__ __launch_bounds__(128) void k_gemm2(
        const __half* __restrict__ Y, const u16* __restrict__ Wh,
        const u16* __restrict__ Wl, const float* __restrict__ dinv,
        __half* __restrict__ Hh, int N) {
    gemm_f16_body<128>(Y, Wh, Wl, dinv, Hh, N);
}
__global__ __launch_bounds__(128) void k_gemm3(
        const __half* __restrict__ Y, const u16* __restrict__ Wh,
        const u16* __restrict__ Wl, const float* __restrict__ dinv,
        __half* __restrict__ Hh, int N) {
    gemm_f16_body<64>(Y, Wh, Wl, dinv, Hh, N);
}

// --- agg, F=128, fp16 H' in, fp16 y out (leaky-relu) --------------------------
__global__ __launch_bounds__(256) void k_agg128(const __half* __restrict__ Hh,
                                                const int* __restrict__ offs,
                                                const int* __restrict__ csr,
                                                const float* __restrict__ dinv,
                                                const float* __restrict__ bias,
                                                __half* __restrict__ Y, int N) {
    int node = blockIdx.x * 4 + (threadIdx.x >> 6);
    int lane = threadIdx.x & 63;
    if (node >= N) return;
    const __half2* H2 = (const __half2*)Hh;   // row = 64 half2
    float ax = 0.f, ay = 0.f;
    int o0 = offs[node], o1 = offs[node + 1];
    int e = o0;
    for (; e + 4 <= o1; e += 4) {
        int s0 = csr[e], s1 = csr[e + 1], s2 = csr[e + 2], s3 = csr[e + 3];
        float2 f0 = __half22float2(H2[(size_t)s0 * 64 + lane]);
        float2 f1 = __half22float2(H2[(size_t)s1 * 64 + lane]);
        float2 f2 = __half22float2(H2[(size_t)s2 * 64 + lane]);
        float2 f3 = __half22float2(H2[(size_t)s3 * 64 + lane]);
        ax += (f0.x + f1.x) + (f2.x + f3.x);
        ay += (f0.y + f1.y) + (f2.y + f3.y);
    }
    for (; e < o1; ++e) {
        float2 f0 = __half22float2(H2[(size_t)csr[e] * 64 + lane]);
        ax += f0.x; ay += f0.y;
    }
    float2 fs = __half22float2(H2[(size_t)node * 64 + lane]);
    float di = dinv[node];
    float2 bv = ((const float2*)bias)[lane];
    float vx = di * (ax + fs.x) + bv.x;
    float vy = di * (ay + fs.y) + bv.y;
    vx = vx > 0.f ? vx : 0.2f * vx;
    vy = vy > 0.f ? vy : 0.2f * vy;
    ((__half2*)Y)[(size_t)node * 64 + lane] = __floats2half2_rn(vx, vy);
}

// --- agg, F=64, fp16 H' in — shared body, fp16-y or f32-out variants ---------
template <bool RELU, bool OUT16>
__device__ __forceinline__ void agg64_body(const __half* __restrict__ Hh,
                                           const int* __restrict__ offs,
                                           const int* __restrict__ csr,
                                           const float* __restrict__ dinv,
                                           const float* __restrict__ bias,
                                           void* __restrict__ Y, int N) {
    int node = blockIdx.x * 8 + (threadIdx.x >> 5);
    int lane = threadIdx.x & 31;
    if (node >= N) return;
    const __half2* H2 = (const __half2*)Hh;   // row = 32 half2
    float ax = 0.f, ay = 0.f;
    int o0 = offs[node], o1 = offs[node + 1];
    int e = o0;
    for (; e + 4 <= o1; e += 4) {
        int s0 = csr[e], s1 = csr[e + 1], s2 = csr[e + 2], s3 = csr[e + 3];
        float2 f0 = __half22float2(H2[(size_t)s0 * 32 + lane]);
        float2 f1 = __half22float2(H2[(size_t)s1 * 32 + lane]);
        float2 f2 = __half22float2(H2[(size_t)s2 * 32 + lane]);
        float2 f3 = __half22float2(H2[(size_t)s3 * 32 + lane]);
        ax += (f0.x + f1.x) + (f2.x + f3.x);
        ay += (f0.y + f1.y) + (f2.y + f3.y);
    }
    for (; e < o1; ++e) {
        float2 f0 = __half22float2(H2[(size_t)csr[e] * 32 + lane]);
        ax += f0.x; ay += f0.y;
    }
    float2 fs = __half22float2(H2[(size_t)node * 32 + lane]);
    float di = dinv[node];
    float2 bv = ((const float2*)bias)[lane];
    float vx = di * (ax + fs.x) + bv.x;
    float vy = di * (ay + fs.y) + bv.y;
    if (RELU) { vx = vx > 0.f ? vx : 0.2f * vx; vy = vy > 0.f ? vy : 0.2f * vy; }
    if (OUT16)
        ((__half2*)Y)[(size_t)node * 32 + lane] = __floats2half2_rn(vx, vy);
    else
        ((float2*)Y)[(size_t)node * 32 + lane] = make_float2(vx, vy);
}

__global__ __launch_bounds__(256) void k_agg64y(const __half* Hh, const int* offs,
                                                const int* csr, const float* dinv,
                                                const float* bias, __half* Y, int N) {
    agg64_body<true, true>(Hh, offs, csr, dinv, bias, Y, N);
}
__global__ __launch_bounds__(256) void k_agg64out(const __half* Hh, const int* offs,
                                                  const int* csr, const float* dinv,
                                                  const float* bias, float* Y, int N) {
    agg64_body<false, false>(Hh, offs, csr, dinv, bias, Y, N);
}

extern "C" void kernel_launch(void* const* d_in, const int* in_sizes, int n_in,
                              void* d_out, int out_size, void* d_ws, size_t ws_size,
                              hipStream_t stream) {
    const float* x  = (const float*)d_in[0];
    const int*   ei = (const int*)d_in[1];
    const float* W1 = (const float*)d_in[2];
    const float* b1 = (const float*)d_in[3];
    const float* W2 = (const float*)d_in[4];
    const float* b2 = (const float*)d_in[5];
    const float* W3 = (const float*)d_in[6];
    const float* b3 = (const float*)d_in[7];

    const int N = in_sizes[0] / 512;
    const int E = in_sizes[1] / 2;
    const int nb = (N + 255) / 256;

    char* w = (char*)d_ws;
    auto take = [&](size_t bytes) -> char* {
        char* p = w;
        w += alignup(bytes, 256);
        return p;
    };
    int*    flag  = (int*)take(256);
    int*    deg   = (int*)take((size_t)N * 4);
    int*    offs  = (int*)take((size_t)(N + 1) * 4);
    int*    bsums = (int*)take((size_t)nb * 4);
    int*    csr   = (int*)take((size_t)E * 4);
    float*  dinv  = (float*)take((size_t)N * 4);
    __half* bufA  = (__half*)take((size_t)N * 128 * 2);   // H' fp16
    __half* bufY  = (__half*)take((size_t)N * 128 * 2);   // y fp16
    u16*    w1h   = (u16*)take((size_t)512 * 128 * 2);
    u16*    w1l   = (u16*)take((size_t)512 * 128 * 2);
    u16*    w2h   = (u16*)take((size_t)128 * 64 * 2);
    u16*    w2l   = (u16*)take((size_t)128 * 64 * 2);
    u16*    w3h   = (u16*)take((size_t)64 * 64 * 2);
    u16*    w3l   = (u16*)take((size_t)64 * 64 * 2);

    const int TB = 256;
    // preprocessing (5 launches)
    k_init_split<<<nb + 38, TB, 0, stream>>>(ei, flag, deg, N, nb,
                                             W1, w1h, w1l, W2, w2h, w2l,
                                             W3, w3h, w3l);
    k_deg<<<(E + TB - 1) / TB, TB, 0, stream>>>(ei, E, flag, deg);
    k_scan1<<<nb, 256, 0, stream>>>(deg, offs, bsums, dinv, N);
    k_scan23<<<nb, 256, 0, stream>>>(offs, bsums, nb, N, E);
    k_fill<<<(E + TB - 1) / TB, TB, 0, stream>>>(ei, E, flag, offs, deg, csr);

    const int rowtiles = (N + 63) / 64;
    // layer 1: 4-wave blocks, shared A stage, col-quarter waves
    k_gemm_bf16<<<rowtiles, 256, 0, stream>>>(x, w1h, w1l, dinv, bufA, N);
    k_agg128<<<(N + 3) / 4, 256, 0, stream>>>(bufA, offs, csr, dinv, b1, bufY, N);
    // layer 2
    k_gemm2<<<rowtiles, 128, 0, stream>>>(bufY, w2h, w2l, dinv, bufA, N);
    k_agg64y<<<(N + 7) / 8, 256, 0, stream>>>(bufA, offs, csr, dinv, b2, bufY, N);
    // layer 3
    k_gemm3<<<rowtiles, 128, 0, stream>>>(bufY, w3h, w3l, dinv, bufA, N);
    k_agg64out<<<(N + 7) / 8, 256, 0, stream>>>(bufA, offs, csr, dinv, b3,
                                                (float*)d_out, N);
}

// Round 18
// 227.382 us; speedup vs baseline: 1.1783x; 1.0947x over previous
//
#include <hip/hip_runtime.h>
#include <hip/hip_fp16.h>

// ---------------------------------------------------------------------------
// GCN 3-layer forward on MI355X.  (r18: r14 known-good + 8-edge agg unroll)
// init+splitW -> deg -> scan1(+dinv) -> scan23 -> fill -> per layer:
//   L1: k_gemm_bf16 (X f32, bf16x3 split, LDS-staged, 2-wave blocks)
//       -> k_agg128 (y1 fp16)
//   L2: k_gemm2 (A=y1 fp16 EXACT, W fp16-split, 2 MFMA prods) -> k_agg64y
//   L3: k_gemm3 -> k_agg64out (f32 d_out)
// r17 post-mortem: "full-width" NF=4 covered only cols 0-63 of 128 -> fail.
// Reverted to r14 structure (231us best-passing). This round: agg kernels
// unroll 8 edges/iter (8 gathers in flight vs 4) - they are latency-bound
// on the dependent csr->row chain, not BW-bound.
// ---------------------------------------------------------------------------

typedef __attribute__((ext_vector_type(8))) short bf16x8;
typedef __attribute__((ext_vector_type(8))) _Float16 f16x8;
typedef __attribute__((ext_vector_type(4))) float f32x4;
typedef unsigned short u16;
typedef unsigned int u32;

static inline size_t alignup(size_t v, size_t a) { return (v + a - 1) & ~(a - 1); }

__device__ __forceinline__ u32 pack_hi16(u32 b0, u32 b1) {
    return __builtin_amdgcn_perm(b1, b0, 0x07060302u);   // top16(b0)|top16(b1)
}

// --- W1 split: fragment-ordered bf16 hi/lo -----------------------------------
__device__ __forceinline__ void splitW_bf16(const float* __restrict__ W,
                                            u16* __restrict__ Wh,
                                            u16* __restrict__ Wl, int s, int F) {
    int c = s % F;
    int kb = (s / F) * 8;
    union { u32 u[4]; bf16x8 v; } hi, lo;
#pragma unroll
    for (int p = 0; p < 4; p++) {
        float x0 = W[(size_t)(kb + 2 * p) * F + c];
        float x1 = W[(size_t)(kb + 2 * p + 1) * F + c];
        u32 b0 = __float_as_uint(x0), b1 = __float_as_uint(x1);
        float l0 = x0 - __uint_as_float(b0 & 0xFFFF0000u);
        float l1 = x1 - __uint_as_float(b1 & 0xFFFF0000u);
        hi.u[p] = pack_hi16(b0, b1);
        lo.u[p] = pack_hi16(__float_as_uint(l0), __float_as_uint(l1));
    }
    *(bf16x8*)(Wh + (size_t)s * 8) = hi.v;
    *(bf16x8*)(Wl + (size_t)s * 8) = lo.v;
}

// --- W2/W3 split: fragment-ordered fp16 hi/lo (22-bit effective) -------------
__device__ __forceinline__ void splitW_f16(const float* __restrict__ W,
                                           u16* __restrict__ Wh,
                                           u16* __restrict__ Wl, int s, int F) {
    int c = s % F;
    int kb = (s / F) * 8;
    union { u16 u[8]; bf16x8 v; } hi, lo;
#pragma unroll
    for (int p = 0; p < 8; p++) {
        float xv = W[(size_t)(kb + p) * F + c];
        __half h = __float2half(xv);
        __half l = __float2half(xv - __half2float(h));
        hi.u[p] = __half_as_ushort(h);
        lo.u[p] = __half_as_ushort(l);
    }
    *(bf16x8*)(Wh + (size_t)s * 8) = hi.v;
    *(bf16x8*)(Wl + (size_t)s * 8) = lo.v;
}

// --- init (zero deg + detect layout) fused with W splits ---------------------
__global__ void k_init_split(const int* __restrict__ ei, int* __restrict__ flag,
                             int* __restrict__ deg, int N, int nb,
                             const float* __restrict__ W1, u16* w1h, u16* w1l,
                             const float* __restrict__ W2, u16* w2h, u16* w2l,
                             const float* __restrict__ W3, u16* w3h, u16* w3l) {
    int b = blockIdx.x;
    if (b < nb) {
        int i = b * 256 + threadIdx.x;
        if (i < N) deg[i] = 0;
        if (b == 0 && threadIdx.x < 64) {
            int v = ei[2 * threadIdx.x + 1];          // high word if int64
            unsigned long long m = __ballot(v != 0);
            if (threadIdx.x == 0) *flag = (m == 0ull) ? 1 : 0;
        }
        return;
    }
    int s = (b - nb) * 256 + threadIdx.x;
    if (s < 8192) splitW_bf16(W1, w1h, w1l, s, 128);              // 512x128/8
    else if (s < 9216) splitW_f16(W2, w2h, w2l, s - 8192, 64);    // 128x64/8
    else if (s < 9728) splitW_f16(W3, w3h, w3l, s - 9216, 64);    // 64x64/8
}

__global__ void k_deg(const int* __restrict__ ei, int E,
                      const int* __restrict__ flag, int* __restrict__ deg) {
    int i = blockIdx.x * blockDim.x + threadIdx.x;
    if (i >= E) return;
    int is64 = *flag;
    int d = is64 ? ei[2 * (E + i)] : ei[E + i];
    atomicAdd(&deg[d], 1);
}

__global__ void k_scan1(const int* __restrict__ deg, int* __restrict__ offs,
                        int* __restrict__ bsums, float* __restrict__ dinv, int N) {
    __shared__ int s[256];
    int i = blockIdx.x * 256 + threadIdx.x;
    int v = (i < N) ? deg[i] : 0;
    if (i < N) dinv[i] = rsqrtf((float)v + 1.0f);
    s[threadIdx.x] = v;
    __syncthreads();
    for (int off = 1; off < 256; off <<= 1) {
        int t = (threadIdx.x >= off) ? s[threadIdx.x - off] : 0;
        __syncthreads();
        s[threadIdx.x] += t;
        __syncthreads();
    }
    if (i < N) offs[i] = s[threadIdx.x] - v;   // exclusive
    if (threadIdx.x == 255) bsums[blockIdx.x] = s[255];
}

__global__ void k_scan23(int* __restrict__ offs, const int* __restrict__ bsums,
                         int nb, int N, int E) {
    __shared__ int s[256];
    int tid = threadIdx.x;
    s[tid] = (tid < nb) ? bsums[tid] : 0;
    __syncthreads();
    for (int off = 1; off < 256; off <<= 1) {
        int t = (tid >= off) ? s[tid - off] : 0;
        __syncthreads();
        s[tid] += t;                 // inclusive scan
        __syncthreads();
    }
    int boff = (blockIdx.x > 0) ? s[blockIdx.x - 1] : 0;
    int i = blockIdx.x * 256 + tid;
    if (i < N) offs[i] += boff;
    if (i == 0) offs[N] = E;
}

__global__ void k_fill(const int* __restrict__ ei, int E,
                       const int* __restrict__ flag,
                       const int* __restrict__ offs, int* __restrict__ deg,
                       int* __restrict__ csr) {
    int i = blockIdx.x * blockDim.x + threadIdx.x;
    if (i >= E) return;
    int is64 = *flag;
    int s = is64 ? ei[2 * i] : ei[i];
    int d = is64 ? ei[2 * (E + i)] : ei[E + i];
    int slot = offs[d] + atomicSub(&deg[d], 1) - 1;
    csr[slot] = s;
}

// --- L1 GEMM: H'[N,128] = dinv * (X[N,512] @ W1), bf16x3, fp16 out -----------
// r11/r14 structure: 128 thr = 2 waves (col halves), wave tile 64x64
// (MF=4, NF=4), A K-tile [64][32] f32 dbuf LDS via global_load_lds
// (src chunk-swizzle c^=(row&7)).
__global__ __launch_bounds__(128) void k_gemm_bf16(
        const float* __restrict__ X,
        const u16* __restrict__ Wh, const u16* __restrict__ Wl,
        const float* __restrict__ dinv, __half* __restrict__ Hh, int N) {
    constexpr int K = 512, F = 128, MF = 4, NF = 4, NT = K / 32;
    __shared__ float4 smemA[2][512];   // 2 x 8 KB

    const int tid = threadIdx.x;
    const int lane = tid & 63;
    const int w = tid >> 6;
    const int colbase = w * (NF * 16);
    const int lg = lane >> 4, li = lane & 15;
    const int row0 = blockIdx.x * 64;

    auto stage = [&](int b, int t) {
#pragma unroll
        for (int j = 0; j < 4; j++) {
            int c_lin = j * 128 + tid;
            int row = c_lin >> 3, c = c_lin & 7;
            int rg = row0 + row;
            if (rg >= N) rg = N - 1;
            int cs = c ^ (row & 7);
            const float* g = X + (size_t)rg * K + t * 32 + cs * 4;
            char* l = (char*)&smemA[b][0] + j * 2048 + w * 1024;
            __builtin_amdgcn_global_load_lds(
                (const __attribute__((address_space(1))) void*)g,
                (__attribute__((address_space(3))) void*)l, 16, 0, 0);
        }
    };

    f32x4 acc[MF][NF];
#pragma unroll
    for (int m = 0; m < MF; m++)
#pragma unroll
        for (int n = 0; n < NF; n++) acc[m][n] = (f32x4){0.f, 0.f, 0.f, 0.f};

    stage(0, 0);
    __syncthreads();

    for (int t = 0; t < NT; t++) {
        const int b = t & 1;
        bf16x8 bh[NF], bl[NF];
        size_t slot0 = (size_t)(t * 4 + lg) * F + colbase + li;
#pragma unroll
        for (int n = 0; n < NF; n++) {
            bh[n] = *(const bf16x8*)(Wh + (slot0 + n * 16) * 8);
            bl[n] = *(const bf16x8*)(Wl + (slot0 + n * 16) * 8);
        }
        __builtin_amdgcn_sched_barrier(0);
        if (t + 1 < NT) stage(b ^ 1, t + 1);
        const float4* lt = &smemA[b][0];
        bf16x8 ah[MF], al[MF];
#pragma unroll
        for (int m = 0; m < MF; m++) {
            int row = m * 16 + li;
            int base = row * 8, sw = row & 7;
            float4 c0 = lt[base + ((2 * lg) ^ sw)];
            float4 c1 = lt[base + ((2 * lg + 1) ^ sw)];
            float xv[8] = {c0.x, c0.y, c0.z, c0.w, c1.x, c1.y, c1.z, c1.w};
            union { u32 u[4]; bf16x8 v; } hi, lo;
#pragma unroll
            for (int q = 0; q < 4; q++) {
                u32 b0 = __float_as_uint(xv[2 * q]);
                u32 b1 = __float_as_uint(xv[2 * q + 1]);
                float l0 = xv[2 * q]     - __uint_as_float(b0 & 0xFFFF0000u);
                float l1 = xv[2 * q + 1] - __uint_as_float(b1 & 0xFFFF0000u);
                hi.u[q] = pack_hi16(b0, b1);
                lo.u[q] = pack_hi16(__float_as_uint(l0), __float_as_uint(l1));
            }
            ah[m] = hi.v;
            al[m] = lo.v;
        }
#pragma unroll
        for (int m = 0; m < MF; m++)
#pragma unroll
            for (int n = 0; n < NF; n++) {
                acc[m][n] = __builtin_amdgcn_mfma_f32_16x16x32_bf16(ah[m], bh[n], acc[m][n], 0, 0, 0);
                acc[m][n] = __builtin_amdgcn_mfma_f32_16x16x32_bf16(ah[m], bl[n], acc[m][n], 0, 0, 0);
                acc[m][n] = __builtin_amdgcn_mfma_f32_16x16x32_bf16(al[m], bh[n], acc[m][n], 0, 0, 0);
            }
        __syncthreads();
    }

#pragma unroll
    for (int m = 0; m < MF; m++) {
        int rb = row0 + m * 16 + lg * 4;
#pragma unroll
        for (int r = 0; r < 4; r++) {
            int gr = rb + r;
            if (gr >= N) continue;
            float di = dinv[gr];
#pragma unroll
            for (int n = 0; n < NF; n++) {
                int col = colbase + n * 16 + li;
                Hh[(size_t)gr * F + col] = __float2half(acc[m][n][r] * di);
            }
        }
    }
}

// --- L2/L3 GEMM body: H'[N,64] = dinv * (Y[N,K] @ W), Y fp16 EXACT -----------
// 128 thr = 2 waves (col halves), wave tile 64x32 (MF=4, NF=2), 2 MFMA prods.
template <int K>
__device__ __forceinline__ void gemm_f16_body(
        const __half* __restrict__ Y,
        const u16* __restrict__ Wh, const u16* __restrict__ Wl,
        const float* __restrict__ dinv, __half* __restrict__ Hh, int N) {
    constexpr int F = 64, MF = 4, NF = 2, NT = K / 32;
    __shared__ float4 smemA[2][256];   // 2 x 4 KB

    const int tid = threadIdx.x;
    const int lane = tid & 63;
    const int w = tid >> 6;
    const int colbase = w * (NF * 16);
    const int lg = lane >> 4, li = lane & 15;
    const int row0 = blockIdx.x * 64;

    auto stage = [&](int b, int t) {
#pragma unroll
        for (int j = 0; j < 2; j++) {
            int c_lin = j * 128 + tid;          // 0..255
            int row = c_lin >> 2, c = c_lin & 3;
            int rg = row0 + row;
            if (rg >= N) rg = N - 1;
            int cs = c ^ (row & 3);
            const __half* g = Y + (size_t)rg * K + t * 32 + cs * 8;  // 16 B
            char* l = (char*)&smemA[b][0] + j * 2048 + w * 1024;
            __builtin_amdgcn_global_load_lds(
                (const __attribute__((address_space(1))) void*)g,
                (__attribute__((address_space(3))) void*)l, 16, 0, 0);
        }
    };

    f32x4 acc[MF][NF];
#pragma unroll
    for (int m = 0; m < MF; m++)
#pragma unroll
        for (int n = 0; n < NF; n++) acc[m][n] = (f32x4){0.f, 0.f, 0.f, 0.f};

    stage(0, 0);
    __syncthreads();

    for (int t = 0; t < NT; t++) {
        const int b = t & 1;
        f16x8 bh[NF], bl[NF];
        size_t slot0 = (size_t)(t * 4 + lg) * F + colbase + li;
#pragma unroll
        for (int n = 0; n < NF; n++) {
            bh[n] = *(const f16x8*)(Wh + (slot0 + n * 16) * 8);
            bl[n] = *(const f16x8*)(Wl + (slot0 + n * 16) * 8);
        }
        __builtin_amdgcn_sched_barrier(0);
        if (t + 1 < NT) stage(b ^ 1, t + 1);
        const float4* lt = &smemA[b][0];
        f16x8 a[MF];
#pragma unroll
        for (int m = 0; m < MF; m++) {
            int row = m * 16 + li;
            union { float4 f; f16x8 h; } u;
            u.f = lt[row * 4 + (lg ^ (row & 3))];
            a[m] = u.h;
        }
#pragma unroll
        for (int m = 0; m < MF; m++)
#pragma unroll
            for (int n = 0; n < NF; n++) {
                acc[m][n] = __builtin_amdgcn_mfma_f32_16x16x32_f16(a[m], bh[n], acc[m][n], 0, 0, 0);
                acc[m][n] = __builtin_amdgcn_mfma_f32_16x16x32_f16(a[m], bl[n], acc[m][n], 0, 0, 0);
            }
        __syncthreads();
    }

#pragma unroll
    for (int m = 0; m < MF; m++) {
        int rb = row0 + m * 16 + lg * 4;
#pragma unroll
        for (int r = 0; r < 4; r++) {
            int gr = rb + r;
            if (gr >= N) continue;
            float di = dinv[gr];
#pragma unroll
            for (int n = 0; n < NF; n++) {
                int col = colbase + n * 16 + li;
                Hh[(size_t)gr * F + col] = __float2half(acc[m][n][r] * di);
            }
        }
    }
}

__global__ __launch_bounds__(128) void k_gemm2(
        const __half* __restrict__ Y, const u16* __restrict__ Wh,
        const u16* __restrict__ Wl, const float* __restrict__ dinv,
        __half* __restrict__ Hh, int N) {
    gemm_f16_body<128>(Y, Wh, Wl, dinv, Hh, N);
}
__global__ __launch_bounds__(128) void k_gemm3(
        const __half* __restrict__ Y, const u16* __restrict__ Wh,
        const u16* __restrict__ Wl, const float* __restrict__ dinv,
        __half* __restrict__ Hh, int N) {
    gemm_f16_body<64>(Y, Wh, Wl, dinv, Hh, N);
}

// --- agg, F=128, fp16 H' in, fp16 y out (leaky-relu); 8-edge unroll -----------
__global__ __launch_bounds__(256) void k_agg128(const __half* __restrict__ Hh,
                                                const int* __restrict__ offs,
                                                const int* __restrict__ csr,
                                                const float* __restrict__ dinv,
                                                const float* __restrict__ bias,
                                                __half* __restrict__ Y, int N) {
    int node = blockIdx.x * 4 + (threadIdx.x >> 6);
    int lane = threadIdx.x & 63;
    if (node >= N) return;
    const __half2* H2 = (const __half2*)Hh;   // row = 64 half2
    float ax = 0.f, ay = 0.f;
    int o0 = offs[node], o1 = offs[node + 1];
    int e = o0;
    for (; e + 8 <= o1; e += 8) {
        int s[8];
#pragma unroll
        for (int q = 0; q < 8; q++) s[q] = csr[e + q];
        float2 f[8];
#pragma unroll
        for (int q = 0; q < 8; q++)
            f[q] = __half22float2(H2[(size_t)s[q] * 64 + lane]);
#pragma unroll
        for (int q = 0; q < 8; q++) { ax += f[q].x; ay += f[q].y; }
    }
    for (; e + 4 <= o1; e += 4) {
        int s0 = csr[e], s1 = csr[e + 1], s2 = csr[e + 2], s3 = csr[e + 3];
        float2 f0 = __half22float2(H2[(size_t)s0 * 64 + lane]);
        float2 f1 = __half22float2(H2[(size_t)s1 * 64 + lane]);
        float2 f2 = __half22float2(H2[(size_t)s2 * 64 + lane]);
        float2 f3 = __half22float2(H2[(size_t)s3 * 64 + lane]);
        ax += (f0.x + f1.x) + (f2.x + f3.x);
        ay += (f0.y + f1.y) + (f2.y + f3.y);
    }
    for (; e < o1; ++e) {
        float2 f0 = __half22float2(H2[(size_t)csr[e] * 64 + lane]);
        ax += f0.x; ay += f0.y;
    }
    float2 fs = __half22float2(H2[(size_t)node * 64 + lane]);
    float di = dinv[node];
    float2 bv = ((const float2*)bias)[lane];
    float vx = di * (ax + fs.x) + bv.x;
    float vy = di * (ay + fs.y) + bv.y;
    vx = vx > 0.f ? vx : 0.2f * vx;
    vy = vy > 0.f ? vy : 0.2f * vy;
    ((__half2*)Y)[(size_t)node * 64 + lane] = __floats2half2_rn(vx, vy);
}

// --- agg, F=64, fp16 H' in — shared body, fp16-y or f32-out; 8-edge unroll ----
template <bool RELU, bool OUT16>
__device__ __forceinline__ void agg64_body(const __half* __restrict__ Hh,
                                           const int* __restrict__ offs,
                                           const int* __restrict__ csr,
                                           const float* __restrict__ dinv,
                                           const float* __restrict__ bias,
                                           void* __restrict__ Y, int N) {
    int node = blockIdx.x * 8 + (threadIdx.x >> 5);
    int lane = threadIdx.x & 31;
    if (node >= N) return;
    const __half2* H2 = (const __half2*)Hh;   // row = 32 half2
    float ax = 0.f, ay = 0.f;
    int o0 = offs[node], o1 = offs[node + 1];
    int e = o0;
    for (; e + 8 <= o1; e += 8) {
        int s[8];
#pragma unroll
        for (int q = 0; q < 8; q++) s[q] = csr[e + q];
        float2 f[8];
#pragma unroll
        for (int q = 0; q < 8; q++)
            f[q] = __half22float2(H2[(size_t)s[q] * 32 + lane]);
#pragma unroll
        for (int q = 0; q < 8; q++) { ax += f[q].x; ay += f[q].y; }
    }
    for (; e + 4 <= o1; e += 4) {
        int s0 = csr[e], s1 = csr[e + 1], s2 = csr[e + 2], s3 = csr[e + 3];
        float2 f0 = __half22float2(H2[(size_t)s0 * 32 + lane]);
        float2 f1 = __half22float2(H2[(size_t)s1 * 32 + lane]);
        float2 f2 = __half22float2(H2[(size_t)s2 * 32 + lane]);
        float2 f3 = __half22float2(H2[(size_t)s3 * 32 + lane]);
        ax += (f0.x + f1.x) + (f2.x + f3.x);
        ay += (f0.y + f1.y) + (f2.y + f3.y);
    }
    for (; e < o1; ++e) {
        float2 f0 = __half22float2(H2[(size_t)csr[e] * 32 + lane]);
        ax += f0.x; ay += f0.y;
    }
    float2 fs = __half22float2(H2[(size_t)node * 32 + lane]);
    float di = dinv[node];
    float2 bv = ((const float2*)bias)[lane];
    float vx = di * (ax + fs.x) + bv.x;
    float vy = di * (ay + fs.y) + bv.y;
    if (RELU) { vx = vx > 0.f ? vx : 0.2f * vx; vy = vy > 0.f ? vy : 0.2f * vy; }
    if (OUT16)
        ((__half2*)Y)[(size_t)node * 32 + lane] = __floats2half2_rn(vx, vy);
    else
        ((float2*)Y)[(size_t)node * 32 + lane] = make_float2(vx, vy);
}

__global__ __launch_bounds__(256) void k_agg64y(const __half* Hh, const int* offs,
                                                const int* csr, const float* dinv,
                                                const float* bias, __half* Y, int N) {
    agg64_body<true, true>(Hh, offs, csr, dinv, bias, Y, N);
}
__global__ __launch_bounds__(256) void k_agg64out(const __half* Hh, const int* offs,
                                                  const int* csr, const float* dinv,
                                                  const float* bias, float* Y, int N) {
    agg64_body<false, false>(Hh, offs, csr, dinv, bias, Y, N);
}

extern "C" void kernel_launch(void* const* d_in, const int* in_sizes, int n_in,
                              void* d_out, int out_size, void* d_ws, size_t ws_size,
                              hipStream_t stream) {
    const float* x  = (const float*)d_in[0];
    const int*   ei = (const int*)d_in[1];
    const float* W1 = (const float*)d_in[2];
    const float* b1 = (const float*)d_in[3];
    const float* W2 = (const float*)d_in[4];
    const float* b2 = (const float*)d_in[5];
    const float* W3 = (const float*)d_in[6];
    const float* b3 = (const float*)d_in[7];

    const int N = in_sizes[0] / 512;
    const int E = in_sizes[1] / 2;
    const int nb = (N + 255) / 256;

    char* w = (char*)d_ws;
    auto take = [&](size_t bytes) -> char* {
        char* p = w;
        w += alignup(bytes, 256);
        return p;
    };
    int*    flag  = (int*)take(256);
    int*    deg   = (int*)take((size_t)N * 4);
    int*    offs  = (int*)take((size_t)(N + 1) * 4);
    int*    bsums = (int*)take((size_t)nb * 4);
    int*    csr   = (int*)take((size_t)E * 4);
    float*  dinv  = (float*)take((size_t)N * 4);
    __half* bufA  = (__half*)take((size_t)N * 128 * 2);   // H' fp16
    __half* bufY  = (__half*)take((size_t)N * 128 * 2);   // y fp16
    u16*    w1h   = (u16*)take((size_t)512 * 128 * 2);
    u16*    w1l   = (u16*)take((size_t)512 * 128 * 2);
    u16*    w2h   = (u16*)take((size_t)128 * 64 * 2);
    u16*    w2l   = (u16*)take((size_t)128 * 64 * 2);
    u16*    w3h   = (u16*)take((size_t)64 * 64 * 2);
    u16*    w3l   = (u16*)take((size_t)64 * 64 * 2);

    const int TB = 256;
    // preprocessing (5 launches)
    k_init_split<<<nb + 38, TB, 0, stream>>>(ei, flag, deg, N, nb,
                                             W1, w1h, w1l, W2, w2h, w2l,
                                             W3, w3h, w3l);
    k_deg<<<(E + TB - 1) / TB, TB, 0, stream>>>(ei, E, flag, deg);
    k_scan1<<<nb, 256, 0, stream>>>(deg, offs, bsums, dinv, N);
    k_scan23<<<nb, 256, 0, stream>>>(offs, bsums, nb, N, E);
    k_fill<<<(E + TB - 1) / TB, TB, 0, stream>>>(ei, E, flag, offs, deg, csr);

    const int rowtiles = (N + 63) / 64;
    // layer 1
    k_gemm_bf16<<<rowtiles, 128, 0, stream>>>(x, w1h, w1l, dinv, bufA, N);
    k_agg128<<<(N + 3) / 4, 256, 0, stream>>>(bufA, offs, csr, dinv, b1, bufY, N);
    // layer 2
    k_gemm2<<<rowtiles, 128, 0, stream>>>(bufY, w2h, w2l, dinv, bufA, N);
    k_agg64y<<<(N + 7) / 8, 256, 0, stream>>>(bufA, offs, csr, dinv, b2, bufY, N);
    // layer 3
    k_gemm3<<<rowtiles, 128, 0, stream>>>(bufY, w3h, w3l, dinv, bufA, N);
    k_agg64out<<<(N + 7) / 8, 256, 0, stream>>>(bufA, offs, csr, dinv, b3,
                                                (float*)d_out, N);
}